// Round 1
// baseline (655.228 us; speedup 1.0000x reference)
//
#include <hip/hip_runtime.h>
#include <hip/hip_bf16.h>

#define THREADS 256
typedef __hip_bfloat16 bf16;

typedef __bf16 v8bf __attribute__((ext_vector_type(8)));
typedef float  v4f  __attribute__((ext_vector_type(4)));
typedef unsigned int v2u __attribute__((ext_vector_type(2)));

__device__ __forceinline__ float bfl(unsigned u){ return __uint_as_float(u << 16); }
__device__ __forceinline__ float bfh(unsigned u){ return __uint_as_float(u & 0xffff0000u); }

// ---------------- CSR build (group edges by destination) ----------------
__global__ void hist_k(const int* __restrict__ ei, int* __restrict__ cnt,
                       int* __restrict__ rank, int E, int ET){
  int i = blockIdx.x*THREADS + threadIdx.x;
  if (i >= ET) return;
  int d = (i < E) ? ei[E + i] : (i - E);   // self-loops appended
  rank[i] = atomicAdd(&cnt[d], 1);
}

__global__ void scan1_k(const int* __restrict__ deg, int* __restrict__ off,
                        int* __restrict__ bsum, int n){
  __shared__ int sh[1024];
  int i = blockIdx.x*1024 + threadIdx.x;
  int v = (i < n) ? deg[i] : 0;
  sh[threadIdx.x] = v;
  __syncthreads();
  for (int s = 1; s < 1024; s <<= 1){
    int t = (threadIdx.x >= s) ? sh[threadIdx.x - s] : 0;
    __syncthreads();
    sh[threadIdx.x] += t;
    __syncthreads();
  }
  if (i < n) off[i+1] = sh[threadIdx.x];
  if (threadIdx.x == 1023) bsum[blockIdx.x] = sh[1023];
}

__global__ void scan2_k(int* __restrict__ bsum, int nb){
  __shared__ int sh[256];
  int v = (threadIdx.x < nb) ? bsum[threadIdx.x] : 0;
  sh[threadIdx.x] = v;
  __syncthreads();
  for (int s = 1; s < 256; s <<= 1){
    int t = (threadIdx.x >= s) ? sh[threadIdx.x - s] : 0;
    __syncthreads();
    sh[threadIdx.x] += t;
    __syncthreads();
  }
  if (threadIdx.x < nb) bsum[threadIdx.x] = sh[threadIdx.x] - v;  // exclusive
}

__global__ void scan3_k(int* __restrict__ off, const int* __restrict__ bsum, int n){
  int i = blockIdx.x*1024 + threadIdx.x;
  if (i < n) off[i+1] += bsum[blockIdx.x];
  if (i == 0) off[0] = 0;
}

__global__ void scatter_k(const int* __restrict__ ei, const int* __restrict__ off,
                          const int* __restrict__ rank, int* __restrict__ csr,
                          int E, int ET){
  int i = blockIdx.x*THREADS + threadIdx.x;
  if (i >= ET) return;
  int s, d;
  if (i < E){ s = ei[i]; d = ei[E+i]; } else { s = i - E; d = i - E; }
  csr[off[d] + rank[i]] = s;
}

// ---------------- weight prep ----------------
__device__ __forceinline__ void wt_do(const float* __restrict__ W, bf16* __restrict__ WT,
                                      int K, int COUT, int i){
  int k = i / COUT, c = i - k*COUT;
  WT[(size_t)c*K + k] = __float2bfloat16(W[i]);
}

__device__ __forceinline__ void va_do(const float* __restrict__ W, const float* __restrict__ as,
                                      const float* __restrict__ ad, bf16* __restrict__ WTX,
                                      int K, int C, int COUT, int i){
  int k = i % K, c6 = i / K;
  int h = (c6 < 3) ? c6 : c6 - 3;
  const float* a = ((c6 < 3) ? as : ad) + h*C;
  const float* wp = W + (size_t)k*COUT + h*C;
  float s = 0.f;
  for (int cc = 0; cc < C; cc++) s += wp[cc]*a[cc];
  WTX[(size_t)(COUT + c6)*K + k] = __float2bfloat16(s);
}

// one launch: all W transposes + fused-alpha extra columns + graph boundaries
__global__ void prep_k(const float* __restrict__ W1, const float* __restrict__ as1, const float* __restrict__ ad1,
                       const float* __restrict__ W2, const float* __restrict__ as2, const float* __restrict__ ad2,
                       const float* __restrict__ W3, const float* __restrict__ as3, const float* __restrict__ ad3,
                       bf16* __restrict__ WT1, bf16* __restrict__ WT2, bf16* __restrict__ WT3,
                       const int* __restrict__ batch, int* __restrict__ goff, int n, int G)
{
  int i = blockIdx.x*THREADS + threadIdx.x;
  if (i < 24576){ wt_do(W1, WT1, 128, 192, i); return; } i -= 24576;
  if (i < 18432){ wt_do(W2, WT2, 192, 96, i); return; }  i -= 18432;
  if (i < 4608) { wt_do(W3, WT3, 96, 48, i); return; }   i -= 4608;
  if (i < 768)  { va_do(W1, as1, ad1, WT1, 128, 64, 192, i); return; } i -= 768;
  if (i < 1152) { va_do(W2, as2, ad2, WT2, 192, 32, 96, i); return; }  i -= 1152;
  if (i < 576)  { va_do(W3, as3, ad3, WT3, 96, 16, 48, i); return; }   i -= 576;
  if (i <= G){
    if (i == G){ goff[G] = n; return; }
    int lo = 0, hi = n;
    while (lo < hi){ int mid = (lo + hi) >> 1; if (batch[mid] < i) lo = mid + 1; else hi = mid; }
    goff[i] = lo;
  }
}

// ---------------- MFMA GEMM fused with alpha: C = A@B, aS/aD from extra tile ----
// CVT=true: A is f32 (layer-1 input x), converted to bf16 in-register — removes the
// standalone convf2b pass (saves 51 MB of HBM traffic + one launch).
template<int K, int COUT, bool CVT>
__global__ void __launch_bounds__(256) gemm_mfma_k(
    const void* __restrict__ Av, const bf16* __restrict__ BT,
    bf16* __restrict__ C, float* __restrict__ aS4, float* __restrict__ aD4,
    int nRowTiles)
{
  int wave = threadIdx.x >> 6, lane = threadIdx.x & 63;
  int rt = blockIdx.x*4 + wave;
  if (rt >= nRowTiles) return;
  int half = lane & 15;
  int quad = lane >> 4;
  v8bf aF[K/32];
  if constexpr (CVT){
    const float* aBase = (const float*)Av + (size_t)(rt*16 + half)*K + quad*8;
    #pragma unroll
    for (int kk = 0; kk < K/32; kk++){
      float4 f0 = *(const float4*)(aBase + kk*32);
      float4 f1 = *(const float4*)(aBase + kk*32 + 4);
      v8bf t;
      t[0] = (__bf16)f0.x; t[1] = (__bf16)f0.y; t[2] = (__bf16)f0.z; t[3] = (__bf16)f0.w;
      t[4] = (__bf16)f1.x; t[5] = (__bf16)f1.y; t[6] = (__bf16)f1.z; t[7] = (__bf16)f1.w;
      aF[kk] = t;
    }
  } else {
    const __bf16* aBase = (const __bf16*)Av + (size_t)(rt*16 + half)*K + quad*8;
    #pragma unroll
    for (int kk = 0; kk < K/32; kk++) aF[kk] = *(const v8bf*)(aBase + kk*32);
  }
  #pragma unroll
  for (int cb = 0; cb < COUT + 16; cb += 16){
    const __bf16* bBase = (const __bf16*)BT + (size_t)(cb + half)*K + quad*8;
    v4f acc = {0.f, 0.f, 0.f, 0.f};
    #pragma unroll
    for (int kk = 0; kk < K/32; kk++)
      acc = __builtin_amdgcn_mfma_f32_16x16x32_bf16(aF[kk], *(const v8bf*)(bBase + kk*32), acc, 0, 0, 0);
    int orow = rt*16 + quad*4;                 // D: col=lane&15, row=quad*4+reg
    if (cb < COUT){
      bf16* cp = C + (size_t)orow*COUT + cb + half;
      #pragma unroll
      for (int r = 0; r < 4; r++)
        cp[(size_t)r*COUT] = __float2bfloat16(acc[r]);
    } else if (half < 6){
      #pragma unroll
      for (int r = 0; r < 4; r++){
        int row = orow + r;
        if (half < 3) aS4[row*4 + half]     = acc[r];
        else          aD4[row*4 + half - 3] = acc[r];
      }
    }
  }
}

// ---------------- fused softmax-weight + aggregation (GRP lanes per dst node) -------
// Persistent grid-stride waves: each wave loops over many nodes (removes per-node
// wave setup/drain and 25k-block dispatch churn; raises occupancy & loads-in-flight).
// Phase A: lane q computes edge (base+q)'s 3 exp-weights, stores {w_h, byteoff(src)}.
// Phase B: active lanes stream their OWN head's array via broadcast ds_read_b128;
// gathers use uniform-base + 32-bit offset (byteoff precomputed once per edge in A).
template<int HC, int CSH, int GRP>
__global__ void __launch_bounds__(256) agg_k(
    const int* __restrict__ off, const int* __restrict__ csr,
    const bf16* __restrict__ hbuf,
    const float* __restrict__ aS4, const float* __restrict__ aD4,
    const float* __restrict__ bias,
    float* __restrict__ outF, bf16* __restrict__ outB,
    int n, int doElu)
{
  constexpr int NPW = 64 / GRP;
  __shared__ __align__(16) float wls[4][384];   // per wave: NPW groups x 3 heads x GRP float2
  int tid = threadIdx.x;
  int wave = tid >> 6;
  int lane = tid & 63;
  int q = lane % GRP;
  int grp = lane / GRP;
  const int hq = (4*q) >> CSH;               // head of this lane's 4 channels
  const bool act = q < HC/4;
  const unsigned q8 = 8u*q;                  // byte offset of this lane's 4 bf16 channels
  float* gbase = &wls[wave][grp*3*GRP*2];    // this group's region
  const float* wh = gbase + hq*GRP*2;        // own-head stream (phase B)
  const char* hb = (const char*)hbuf;
  float4 bv = {0.f, 0.f, 0.f, 0.f};
  if (act) bv = *(const float4*)(bias + 4*q);

  int nodeTot = (n + NPW - 1) / NPW;
  int nwv = gridDim.x * 4;
  for (int wv = (blockIdx.x*256 + tid) >> 6; wv < nodeTot; wv += nwv){
    int node = wv*NPW + grp;
    bool valid = node < n;
    int e0 = 0, e1 = 0;
    float4 ad = {0.f, 0.f, 0.f, 0.f};
    if (valid){
      e0 = off[node]; e1 = off[node+1];
      ad = *(const float4*)(aD4 + 4*node);
    }
    float dh = 0.f;
    float a0 = 0.f, a1 = 0.f, a2 = 0.f, a3 = 0.f;

    int nch = (e1 - e0 + GRP - 1) / GRP;
    for (int c = 0; c < nch; c++){
      int base = e0 + c*GRP;
      __threadfence_block();                 // WAR: prior chunk's/node's reads drained
      int j = base + q;
      if (j < e1){
        int s = __builtin_nontemporal_load(&csr[j]);
        float4 av = *(const float4*)(aS4 + 4*s);
        float x0 = av.x + ad.x; x0 = (x0 > 0.f) ? x0 : 0.2f*x0;
        float x1 = av.y + ad.y; x1 = (x1 > 0.f) ? x1 : 0.2f*x1;
        float x2 = av.z + ad.z; x2 = (x2 > 0.f) ? x2 : 0.2f*x2;
        float sf = __int_as_float(s * (HC*2));    // precomputed gather byte-offset
        float2 p0 = {__expf(x0), sf};
        float2 p1 = {__expf(x1), sf};
        float2 p2 = {__expf(x2), sf};
        *(float2*)(gbase + (0*GRP + q)*2) = p0;
        *(float2*)(gbase + (1*GRP + q)*2) = p1;
        *(float2*)(gbase + (2*GRP + q)*2) = p2;
      }
      __threadfence_block();                 // writes visible within wave
      if (act){
        int lim = e1 - base; if (lim > GRP) lim = GRP;
        int jj = 0;
        for (; jj + 8 <= lim; jj += 8){
          float4 pA = *(const float4*)(wh + jj*2);        // edges jj, jj+1
          float4 pB = *(const float4*)(wh + jj*2 + 4);    // edges jj+2, jj+3
          float4 pC = *(const float4*)(wh + jj*2 + 8);    // edges jj+4, jj+5
          float4 pD = *(const float4*)(wh + jj*2 + 12);   // edges jj+6, jj+7
          unsigned o0 = __float_as_uint(pA.y) + q8, o1 = __float_as_uint(pA.w) + q8;
          unsigned o2 = __float_as_uint(pB.y) + q8, o3 = __float_as_uint(pB.w) + q8;
          unsigned o4 = __float_as_uint(pC.y) + q8, o5 = __float_as_uint(pC.w) + q8;
          unsigned o6 = __float_as_uint(pD.y) + q8, o7 = __float_as_uint(pD.w) + q8;
          float w0 = pA.x, w1 = pA.z, w2 = pB.x, w3 = pB.z;
          float w4 = pC.x, w5 = pC.z, w6 = pD.x, w7 = pD.z;
          uint2 u0 = *(const uint2*)(hb + o0);
          uint2 u1 = *(const uint2*)(hb + o1);
          uint2 u2 = *(const uint2*)(hb + o2);
          uint2 u3 = *(const uint2*)(hb + o3);
          uint2 u4 = *(const uint2*)(hb + o4);
          uint2 u5 = *(const uint2*)(hb + o5);
          uint2 u6 = *(const uint2*)(hb + o6);
          uint2 u7 = *(const uint2*)(hb + o7);
          dh += w0 + w1 + w2 + w3 + w4 + w5 + w6 + w7;
          a0 += w0*bfl(u0.x); a1 += w0*bfh(u0.x); a2 += w0*bfl(u0.y); a3 += w0*bfh(u0.y);
          a0 += w1*bfl(u1.x); a1 += w1*bfh(u1.x); a2 += w1*bfl(u1.y); a3 += w1*bfh(u1.y);
          a0 += w2*bfl(u2.x); a1 += w2*bfh(u2.x); a2 += w2*bfl(u2.y); a3 += w2*bfh(u2.y);
          a0 += w3*bfl(u3.x); a1 += w3*bfh(u3.x); a2 += w3*bfl(u3.y); a3 += w3*bfh(u3.y);
          a0 += w4*bfl(u4.x); a1 += w4*bfh(u4.x); a2 += w4*bfl(u4.y); a3 += w4*bfh(u4.y);
          a0 += w5*bfl(u5.x); a1 += w5*bfh(u5.x); a2 += w5*bfl(u5.y); a3 += w5*bfh(u5.y);
          a0 += w6*bfl(u6.x); a1 += w6*bfh(u6.x); a2 += w6*bfl(u6.y); a3 += w6*bfh(u6.y);
          a0 += w7*bfl(u7.x); a1 += w7*bfh(u7.x); a2 += w7*bfl(u7.y); a3 += w7*bfh(u7.y);
        }
        for (; jj + 4 <= lim; jj += 4){
          float4 pA = *(const float4*)(wh + jj*2);
          float4 pB = *(const float4*)(wh + jj*2 + 4);
          unsigned o0 = __float_as_uint(pA.y) + q8, o1 = __float_as_uint(pA.w) + q8;
          unsigned o2 = __float_as_uint(pB.y) + q8, o3 = __float_as_uint(pB.w) + q8;
          float w0 = pA.x, w1 = pA.z, w2 = pB.x, w3 = pB.z;
          uint2 u0 = *(const uint2*)(hb + o0);
          uint2 u1 = *(const uint2*)(hb + o1);
          uint2 u2 = *(const uint2*)(hb + o2);
          uint2 u3 = *(const uint2*)(hb + o3);
          dh += w0 + w1 + w2 + w3;
          a0 += w0*bfl(u0.x); a1 += w0*bfh(u0.x); a2 += w0*bfl(u0.y); a3 += w0*bfh(u0.y);
          a0 += w1*bfl(u1.x); a1 += w1*bfh(u1.x); a2 += w1*bfl(u1.y); a3 += w1*bfh(u1.y);
          a0 += w2*bfl(u2.x); a1 += w2*bfh(u2.x); a2 += w2*bfl(u2.y); a3 += w2*bfh(u2.y);
          a0 += w3*bfl(u3.x); a1 += w3*bfh(u3.x); a2 += w3*bfl(u3.y); a3 += w3*bfh(u3.y);
        }
        for (; jj < lim; jj++){
          float2 pw = *(const float2*)(wh + jj*2);
          unsigned o = __float_as_uint(pw.y) + q8;
          float w = pw.x;
          uint2 u = *(const uint2*)(hb + o);
          dh += w;
          a0 += w*bfl(u.x); a1 += w*bfh(u.x); a2 += w*bfl(u.y); a3 += w*bfh(u.y);
        }
      }
    }
    if (act && valid){
      float inv = 1.f / (dh + 1e-16f);
      float r0 = a0*inv + bv.x, r1 = a1*inv + bv.y, r2 = a2*inv + bv.z, r3 = a3*inv + bv.w;
      if (doElu){
        r0 = (r0 > 0.f) ? r0 : (__expf(r0) - 1.f);
        r1 = (r1 > 0.f) ? r1 : (__expf(r1) - 1.f);
        r2 = (r2 > 0.f) ? r2 : (__expf(r2) - 1.f);
        r3 = (r3 > 0.f) ? r3 : (__expf(r3) - 1.f);
      }
      if (outF){
        v4f o = {r0, r1, r2, r3};
        __builtin_nontemporal_store(o, (v4f*)(outF + (size_t)node*HC + 4*q));
      }
      if (outB){
        union { bf16 h[4]; v2u u; } cv;
        cv.h[0] = __float2bfloat16(r0); cv.h[1] = __float2bfloat16(r1);
        cv.h[2] = __float2bfloat16(r2); cv.h[3] = __float2bfloat16(r3);
        __builtin_nontemporal_store(cv.u, (v2u*)(outB + (size_t)node*HC + 4*q));
      }
    }
  }
}

// ---------------- fused mean-pool + relu + linear + sigmoid + BCE (wave per graph) ---
__global__ void __launch_bounds__(256) pool_logits_k(
    const float* __restrict__ h3, const int* __restrict__ goff,
    const float* __restrict__ Wl, const float* __restrict__ bl,
    const float* __restrict__ y, float* __restrict__ outp,
    float* __restrict__ lossAcc, int G)
{
  int lane = threadIdx.x & 63;
  int g = (blockIdx.x*256 + threadIdx.x) >> 6;
  if (g >= G) return;
  int n0 = goff[g], n1 = goff[g+1];
  int cnt = n1 - n0;
  float acc = 0.f, acc2 = 0.f, wl = 0.f;
  if (lane < 48){
    wl = Wl[lane];
    const float* p = h3 + (size_t)n0*48 + lane;
    int i = 0;
    for (; i + 2 <= cnt; i += 2){ acc += p[(size_t)i*48]; acc2 += p[(size_t)(i+1)*48]; }
    if (i < cnt) acc += p[(size_t)i*48];
    acc += acc2;
  }
  float inv = 1.f / fmaxf((float)cnt, 1.f);
  float v = fmaxf(acc*inv, 0.f) * wl;
  for (int o = 32; o > 0; o >>= 1) v += __shfl_down(v, o);
  if (lane == 0){
    float logit = v + bl[0];
    outp[g] = 1.f / (1.f + __expf(-logit));
    float t = y[g];
    float sp = (logit > 0.f) ? (logit + log1pf(__expf(-logit))) : log1pf(__expf(logit));
    atomicAdd(lossAcc, sp - t*logit);
  }
}

__global__ void fin_k(const float* __restrict__ lossAcc, float* __restrict__ outp, int gtot){
  outp[gtot] = lossAcc[0] / (float)gtot;
}

// ---------------- launch ----------------
extern "C" void kernel_launch(void* const* d_in, const int* in_sizes, int n_in,
                              void* d_out, int out_size, void* d_ws, size_t ws_size,
                              hipStream_t stream)
{
  (void)n_in; (void)out_size; (void)ws_size;
  const float* x    = (const float*)d_in[0];
  const float* y    = (const float*)d_in[1];
  const int*  ei    = (const int*)d_in[2];
  const int*  batch = (const int*)d_in[3];
  const float* W1 = (const float*)d_in[4];
  const float* as1= (const float*)d_in[5];
  const float* ad1= (const float*)d_in[6];
  const float* b1 = (const float*)d_in[7];
  const float* W2 = (const float*)d_in[8];
  const float* as2= (const float*)d_in[9];
  const float* ad2= (const float*)d_in[10];
  const float* b2 = (const float*)d_in[11];
  const float* W3 = (const float*)d_in[12];
  const float* as3= (const float*)d_in[13];
  const float* ad3= (const float*)d_in[14];
  const float* b3 = (const float*)d_in[15];
  const float* Wl = (const float*)d_in[16];
  const float* bl = (const float*)d_in[17];
  float* outp = (float*)d_out;

  int Nn = in_sizes[0] / 128;   // 100000 (multiple of 16)
  int Gg = in_sizes[1];
  int Ee = in_sizes[2] / 2;
  int ET = Ee + Nn;

  char* p = (char*)d_ws;
  auto carve = [&](size_t bytes) -> void* {
    void* r = (void*)p; p += (bytes + 255) & ~(size_t)255; return r;
  };
  int*   off     = (int*)  carve((size_t)(Nn+1)*4);
  int*   cnt     = (int*)  carve((size_t)Nn*4);
  int*   csr     = (int*)  carve((size_t)ET*4);
  int*   rank    = (int*)  carve((size_t)ET*4);
  int*   bsum    = (int*)  carve(256*4);
  float* aS4     = (float*)carve((size_t)Nn*4*4);
  float* aD4     = (float*)carve((size_t)Nn*4*4);
  int*   goff    = (int*)  carve((size_t)(Gg+1)*4);
  float* lossAcc = (float*)carve(4);
  bf16*  WT1     = (bf16*) carve((size_t)(192+16)*128*2);
  bf16*  WT2     = (bf16*) carve((size_t)(96+16)*192*2);
  bf16*  WT3     = (bf16*) carve((size_t)(48+16)*96*2);
  bf16*  bufH    = (bf16*) carve((size_t)Nn*192*2);   // GEMM out (h), agg in
  bf16*  bufA    = (bf16*) carve((size_t)Nn*192*2);   // agg out / GEMM A-operand
  // layer-3 f32 out for pooling: alias into the unused tail of bufH's region
  float* bufO    = (float*)((char*)bufH + ((size_t)Nn*96 + 255 & ~(size_t)255));

  int NB = (Nn + 1023) / 1024;
  int ebk = (ET + THREADS - 1) / THREADS;

  // CSR by destination (atomic-free scatter via rank)
  hipMemsetAsync(cnt, 0, (size_t)Nn*4, stream);
  hist_k<<<ebk, THREADS, 0, stream>>>(ei, cnt, rank, Ee, ET);
  scan1_k<<<NB, 1024, 0, stream>>>(cnt, off, bsum, Nn);
  scan2_k<<<1, 256, 0, stream>>>(bsum, NB);
  scan3_k<<<NB, 1024, 0, stream>>>(off, bsum, Nn);
  scatter_k<<<ebk, THREADS, 0, stream>>>(ei, off, rank, csr, Ee, ET);

  // consolidated weight prep + graph boundaries (x->bf16 now fused into gemm1)
  int prepTot = 24576 + 18432 + 4608 + 768 + 1152 + 576 + (Gg + 1);
  prep_k<<<(prepTot + THREADS-1)/THREADS, THREADS, 0, stream>>>(
      W1, as1, ad1, W2, as2, ad2, W3, as3, ad3, WT1, WT2, WT3, batch, goff, Nn, Gg);

  int nRT = Nn / 16;                 // 6250 row tiles
  int gx  = (nRT + 3) / 4;           // 4 waves/block
  int aggGrid = 2048;                // persistent: 8 blocks/CU resident, grid-stride

  // layer 1: 128 -> 3x64 (A = x, f32, converted in-kernel)
  gemm_mfma_k<128,192,true><<<gx, 256, 0, stream>>>(x, WT1, bufH, aS4, aD4, nRT);
  agg_k<192,6,64><<<aggGrid, 256, 0, stream>>>(off, csr, bufH, aS4, aD4, b1, nullptr, bufA, Nn, 1);
  // layer 2: 192 -> 3x32
  gemm_mfma_k<192,96,false><<<gx, 256, 0, stream>>>(bufA, WT2, bufH, aS4, aD4, nRT);
  agg_k<96,5,32><<<aggGrid, 256, 0, stream>>>(off, csr, bufH, aS4, aD4, b2, nullptr, bufA, Nn, 1);
  // layer 3: 96 -> 3x16 (no ELU)
  gemm_mfma_k<96,48,false><<<gx, 256, 0, stream>>>(bufA, WT3, bufH, aS4, aD4, nRT);
  agg_k<48,4,16><<<aggGrid, 256, 0, stream>>>(off, csr, bufH, aS4, aD4, b3, bufO, nullptr, Nn, 0);

  // fused mean pool + relu + linear + sigmoid + BCE loss
  hipMemsetAsync(lossAcc, 0, 4, stream);
  pool_logits_k<<<(Gg + 3)/4, 256, 0, stream>>>(bufO, goff, Wl, bl, y, outp, lossAcc, Gg);
  fin_k<<<1, 1, 0, stream>>>(lossAcc, outp, Gg);
}

// Round 2
// 614.776 us; speedup vs baseline: 1.0658x; 1.0658x over previous
//
#include <hip/hip_runtime.h>
#include <hip/hip_bf16.h>

#define THREADS 256
typedef __hip_bfloat16 bf16;

typedef __bf16 v8bf __attribute__((ext_vector_type(8)));
typedef float  v4f  __attribute__((ext_vector_type(4)));

__device__ __forceinline__ float bfl(unsigned u){ return __uint_as_float(u << 16); }
__device__ __forceinline__ float bfh(unsigned u){ return __uint_as_float(u & 0xffff0000u); }

// ---------------- CSR build (group edges by destination) ----------------
__global__ void hist_k(const int* __restrict__ ei, int* __restrict__ cnt,
                       int* __restrict__ rank, int E, int ET){
  int i = blockIdx.x*THREADS + threadIdx.x;
  if (i >= ET) return;
  int d = (i < E) ? ei[E + i] : (i - E);   // self-loops appended
  rank[i] = atomicAdd(&cnt[d], 1);
}

__global__ void scan1_k(const int* __restrict__ deg, int* __restrict__ off,
                        int* __restrict__ bsum, int n){
  __shared__ int sh[1024];
  int i = blockIdx.x*1024 + threadIdx.x;
  int v = (i < n) ? deg[i] : 0;
  sh[threadIdx.x] = v;
  __syncthreads();
  for (int s = 1; s < 1024; s <<= 1){
    int t = (threadIdx.x >= s) ? sh[threadIdx.x - s] : 0;
    __syncthreads();
    sh[threadIdx.x] += t;
    __syncthreads();
  }
  if (i < n) off[i+1] = sh[threadIdx.x];
  if (threadIdx.x == 1023) bsum[blockIdx.x] = sh[1023];
}

__global__ void scan2_k(int* __restrict__ bsum, int nb){
  __shared__ int sh[256];
  int v = (threadIdx.x < nb) ? bsum[threadIdx.x] : 0;
  sh[threadIdx.x] = v;
  __syncthreads();
  for (int s = 1; s < 256; s <<= 1){
    int t = (threadIdx.x >= s) ? sh[threadIdx.x - s] : 0;
    __syncthreads();
    sh[threadIdx.x] += t;
    __syncthreads();
  }
  if (threadIdx.x < nb) bsum[threadIdx.x] = sh[threadIdx.x] - v;  // exclusive
}

__global__ void scan3_k(int* __restrict__ off, const int* __restrict__ bsum, int n){
  int i = blockIdx.x*1024 + threadIdx.x;
  if (i < n) off[i+1] += bsum[blockIdx.x];
  if (i == 0) off[0] = 0;
}

__global__ void scatter_k(const int* __restrict__ ei, const int* __restrict__ off,
                          const int* __restrict__ rank, int* __restrict__ csr,
                          int E, int ET){
  int i = blockIdx.x*THREADS + threadIdx.x;
  if (i >= ET) return;
  int s, d;
  if (i < E){ s = ei[i]; d = ei[E+i]; } else { s = i - E; d = i - E; }
  csr[off[d] + rank[i]] = s;
}

// ---------------- weight prep ----------------
__device__ __forceinline__ void wt_do(const float* __restrict__ W, bf16* __restrict__ WT,
                                      int K, int COUT, int i){
  int k = i / COUT, c = i - k*COUT;
  WT[(size_t)c*K + k] = __float2bfloat16(W[i]);
}

__device__ __forceinline__ void va_do(const float* __restrict__ W, const float* __restrict__ as,
                                      const float* __restrict__ ad, bf16* __restrict__ WTX,
                                      int K, int C, int COUT, int i){
  int k = i % K, c6 = i / K;
  int h = (c6 < 3) ? c6 : c6 - 3;
  const float* a = ((c6 < 3) ? as : ad) + h*C;
  const float* wp = W + (size_t)k*COUT + h*C;
  float s = 0.f;
  for (int cc = 0; cc < C; cc++) s += wp[cc]*a[cc];
  WTX[(size_t)(COUT + c6)*K + k] = __float2bfloat16(s);
}

// one launch: all W transposes + fused-alpha extra columns + graph boundaries
__global__ void prep_k(const float* __restrict__ W1, const float* __restrict__ as1, const float* __restrict__ ad1,
                       const float* __restrict__ W2, const float* __restrict__ as2, const float* __restrict__ ad2,
                       const float* __restrict__ W3, const float* __restrict__ as3, const float* __restrict__ ad3,
                       bf16* __restrict__ WT1, bf16* __restrict__ WT2, bf16* __restrict__ WT3,
                       const int* __restrict__ batch, int* __restrict__ goff, int n, int G)
{
  int i = blockIdx.x*THREADS + threadIdx.x;
  if (i < 24576){ wt_do(W1, WT1, 128, 192, i); return; } i -= 24576;
  if (i < 18432){ wt_do(W2, WT2, 192, 96, i); return; }  i -= 18432;
  if (i < 4608) { wt_do(W3, WT3, 96, 48, i); return; }   i -= 4608;
  if (i < 768)  { va_do(W1, as1, ad1, WT1, 128, 64, 192, i); return; } i -= 768;
  if (i < 1152) { va_do(W2, as2, ad2, WT2, 192, 32, 96, i); return; }  i -= 1152;
  if (i < 576)  { va_do(W3, as3, ad3, WT3, 96, 16, 48, i); return; }   i -= 576;
  if (i <= G){
    if (i == G){ goff[G] = n; return; }
    int lo = 0, hi = n;
    while (lo < hi){ int mid = (lo + hi) >> 1; if (batch[mid] < i) lo = mid + 1; else hi = mid; }
    goff[i] = lo;
  }
}

// ---------------- MFMA GEMM fused with alpha: C = A@B, aS/aD from extra tile ----
// CVT=true: A is f32 (layer-1 input x), converted to bf16 in-register — removes the
// standalone convf2b pass (saves 77 MB of HBM traffic + one launch).
template<int K, int COUT, bool CVT>
__global__ void __launch_bounds__(256) gemm_mfma_k(
    const void* __restrict__ Av, const bf16* __restrict__ BT,
    bf16* __restrict__ C, float* __restrict__ aS4, float* __restrict__ aD4,
    int nRowTiles)
{
  int wave = threadIdx.x >> 6, lane = threadIdx.x & 63;
  int rt = blockIdx.x*4 + wave;
  if (rt >= nRowTiles) return;
  int half = lane & 15;
  int quad = lane >> 4;
  v8bf aF[K/32];
  if constexpr (CVT){
    const float* aBase = (const float*)Av + (size_t)(rt*16 + half)*K + quad*8;
    #pragma unroll
    for (int kk = 0; kk < K/32; kk++){
      float4 f0 = *(const float4*)(aBase + kk*32);
      float4 f1 = *(const float4*)(aBase + kk*32 + 4);
      v8bf t;
      t[0] = (__bf16)f0.x; t[1] = (__bf16)f0.y; t[2] = (__bf16)f0.z; t[3] = (__bf16)f0.w;
      t[4] = (__bf16)f1.x; t[5] = (__bf16)f1.y; t[6] = (__bf16)f1.z; t[7] = (__bf16)f1.w;
      aF[kk] = t;
    }
  } else {
    const __bf16* aBase = (const __bf16*)Av + (size_t)(rt*16 + half)*K + quad*8;
    #pragma unroll
    for (int kk = 0; kk < K/32; kk++) aF[kk] = *(const v8bf*)(aBase + kk*32);
  }
  #pragma unroll
  for (int cb = 0; cb < COUT + 16; cb += 16){
    const __bf16* bBase = (const __bf16*)BT + (size_t)(cb + half)*K + quad*8;
    v4f acc = {0.f, 0.f, 0.f, 0.f};
    #pragma unroll
    for (int kk = 0; kk < K/32; kk++)
      acc = __builtin_amdgcn_mfma_f32_16x16x32_bf16(aF[kk], *(const v8bf*)(bBase + kk*32), acc, 0, 0, 0);
    int orow = rt*16 + quad*4;                 // D: col=lane&15, row=quad*4+reg
    if (cb < COUT){
      bf16* cp = C + (size_t)orow*COUT + cb + half;
      #pragma unroll
      for (int r = 0; r < 4; r++)
        cp[(size_t)r*COUT] = __float2bfloat16(acc[r]);
    } else if (half < 6){
      #pragma unroll
      for (int r = 0; r < 4; r++){
        int row = orow + r;
        if (half < 3) aS4[row*4 + half]     = acc[r];
        else          aD4[row*4 + half - 3] = acc[r];
      }
    }
  }
}

// ---------------- fused softmax-weight + aggregation (GRP lanes per dst node) -------
// Per-node dispatch (HW scheduler does dynamic load balancing — persistent grid
// measured WORSE: static partition + degree variance = tail imbalance).
// Phase A: lane q computes edge (base+q)'s 3 exp-weights, stores {w_h, byteoff(src)}.
// Phase B: 16-byte gathers — HC/8 active lanes each own 8 channels (uint4), halving
// VMEM instruction count and address VALU vs the 8-byte/48-lane scheme.
template<int HC, int CSH, int GRP>
__global__ void __launch_bounds__(256) agg_k(
    const int* __restrict__ off, const int* __restrict__ csr,
    const bf16* __restrict__ hbuf,
    const float* __restrict__ aS4, const float* __restrict__ aD4,
    const float* __restrict__ bias,
    float* __restrict__ outF, bf16* __restrict__ outB,
    int n, int doElu)
{
  constexpr int NPW = 64 / GRP;
  constexpr int AL  = HC / 8;                // active gather lanes per node
  __shared__ __align__(16) float wls[4][384];   // per wave: NPW groups x 3 heads x GRP float2
  int tid = threadIdx.x;
  int wave = tid >> 6;
  int lane = tid & 63;
  int q = lane % GRP;
  int grp = lane / GRP;
  int wv = (blockIdx.x*256 + tid) >> 6;
  int node = wv*NPW + grp;
  bool valid = node < n;
  int e0 = 0, e1 = 0;
  float4 ad = {0.f, 0.f, 0.f, 0.f};
  if (valid){
    e0 = off[node]; e1 = off[node+1];
    ad = *(const float4*)(aD4 + 4*node);
  }
  const int hq = (8*q) >> CSH;               // head of this lane's 8 channels
  const bool act = valid && (q < AL);
  const unsigned q16 = 16u*q;                // byte offset of this lane's 8 bf16 channels
  float dh = 0.f;
  float a0 = 0.f, a1 = 0.f, a2 = 0.f, a3 = 0.f;
  float a4 = 0.f, a5 = 0.f, a6 = 0.f, a7 = 0.f;
  float* gbase = &wls[wave][grp*3*GRP*2];    // this group's region
  const float* wh = gbase + hq*GRP*2;        // own-head stream (phase B)
  const char* hb = (const char*)hbuf;

#define ACC8(U,W) \
  a0 += (W)*bfl((U).x); a1 += (W)*bfh((U).x); a2 += (W)*bfl((U).y); a3 += (W)*bfh((U).y); \
  a4 += (W)*bfl((U).z); a5 += (W)*bfh((U).z); a6 += (W)*bfl((U).w); a7 += (W)*bfh((U).w);

  int nch = (e1 - e0 + GRP - 1) / GRP;
  for (int c = 0; c < nch; c++){
    int base = e0 + c*GRP;
    __threadfence_block();                   // WAR: prior chunk's reads drained
    int j = base + q;
    if (j < e1){
      int s = csr[j];
      float4 av = *(const float4*)(aS4 + 4*s);
      float x0 = av.x + ad.x; x0 = (x0 > 0.f) ? x0 : 0.2f*x0;
      float x1 = av.y + ad.y; x1 = (x1 > 0.f) ? x1 : 0.2f*x1;
      float x2 = av.z + ad.z; x2 = (x2 > 0.f) ? x2 : 0.2f*x2;
      float sf = __int_as_float(s * (HC*2));    // precomputed gather byte-offset
      float2 p0 = {__expf(x0), sf};
      float2 p1 = {__expf(x1), sf};
      float2 p2 = {__expf(x2), sf};
      *(float2*)(gbase + (0*GRP + q)*2) = p0;
      *(float2*)(gbase + (1*GRP + q)*2) = p1;
      *(float2*)(gbase + (2*GRP + q)*2) = p2;
    }
    __threadfence_block();                   // writes visible within wave
    if (act){
      int lim = e1 - base; if (lim > GRP) lim = GRP;
      int jj = 0;
      for (; jj + 4 <= lim; jj += 4){
        float4 pA = *(const float4*)(wh + jj*2);        // edges jj, jj+1
        float4 pB = *(const float4*)(wh + jj*2 + 4);    // edges jj+2, jj+3
        unsigned o0 = __float_as_uint(pA.y) + q16, o1 = __float_as_uint(pA.w) + q16;
        unsigned o2 = __float_as_uint(pB.y) + q16, o3 = __float_as_uint(pB.w) + q16;
        float w0 = pA.x, w1 = pA.z, w2 = pB.x, w3 = pB.z;
        uint4 u0 = *(const uint4*)(hb + o0);
        uint4 u1 = *(const uint4*)(hb + o1);
        uint4 u2 = *(const uint4*)(hb + o2);
        uint4 u3 = *(const uint4*)(hb + o3);
        dh += w0 + w1 + w2 + w3;
        ACC8(u0, w0);
        ACC8(u1, w1);
        ACC8(u2, w2);
        ACC8(u3, w3);
      }
      for (; jj + 2 <= lim; jj += 2){
        float4 pA = *(const float4*)(wh + jj*2);
        unsigned o0 = __float_as_uint(pA.y) + q16, o1 = __float_as_uint(pA.w) + q16;
        float w0 = pA.x, w1 = pA.z;
        uint4 u0 = *(const uint4*)(hb + o0);
        uint4 u1 = *(const uint4*)(hb + o1);
        dh += w0 + w1;
        ACC8(u0, w0);
        ACC8(u1, w1);
      }
      for (; jj < lim; jj++){
        float2 pw = *(const float2*)(wh + jj*2);
        unsigned o = __float_as_uint(pw.y) + q16;
        float w = pw.x;
        uint4 u = *(const uint4*)(hb + o);
        dh += w;
        ACC8(u, w);
      }
    }
  }
#undef ACC8
  if (act){
    float inv = 1.f / (dh + 1e-16f);
    const float4 bA = *(const float4*)(bias + 8*q);
    const float4 bB = *(const float4*)(bias + 8*q + 4);
    float r0 = a0*inv + bA.x, r1 = a1*inv + bA.y, r2 = a2*inv + bA.z, r3 = a3*inv + bA.w;
    float r4 = a4*inv + bB.x, r5 = a5*inv + bB.y, r6 = a6*inv + bB.z, r7 = a7*inv + bB.w;
    if (doElu){
      r0 = (r0 > 0.f) ? r0 : (__expf(r0) - 1.f);
      r1 = (r1 > 0.f) ? r1 : (__expf(r1) - 1.f);
      r2 = (r2 > 0.f) ? r2 : (__expf(r2) - 1.f);
      r3 = (r3 > 0.f) ? r3 : (__expf(r3) - 1.f);
      r4 = (r4 > 0.f) ? r4 : (__expf(r4) - 1.f);
      r5 = (r5 > 0.f) ? r5 : (__expf(r5) - 1.f);
      r6 = (r6 > 0.f) ? r6 : (__expf(r6) - 1.f);
      r7 = (r7 > 0.f) ? r7 : (__expf(r7) - 1.f);
    }
    if (outF){
      float4 oA = {r0, r1, r2, r3};
      float4 oB = {r4, r5, r6, r7};
      *(float4*)(outF + (size_t)node*HC + 8*q)     = oA;
      *(float4*)(outF + (size_t)node*HC + 8*q + 4) = oB;
    }
    if (outB){
      union { bf16 h[8]; uint4 u; } cv;
      cv.h[0] = __float2bfloat16(r0); cv.h[1] = __float2bfloat16(r1);
      cv.h[2] = __float2bfloat16(r2); cv.h[3] = __float2bfloat16(r3);
      cv.h[4] = __float2bfloat16(r4); cv.h[5] = __float2bfloat16(r5);
      cv.h[6] = __float2bfloat16(r6); cv.h[7] = __float2bfloat16(r7);
      *(uint4*)(outB + (size_t)node*HC + 8*q) = cv.u;
    }
  }
}

// ---------------- fused mean-pool + relu + linear + sigmoid + BCE (wave per graph) ---
__global__ void __launch_bounds__(256) pool_logits_k(
    const float* __restrict__ h3, const int* __restrict__ goff,
    const float* __restrict__ Wl, const float* __restrict__ bl,
    const float* __restrict__ y, float* __restrict__ outp,
    float* __restrict__ lossAcc, int G)
{
  int lane = threadIdx.x & 63;
  int g = (blockIdx.x*256 + threadIdx.x) >> 6;
  if (g >= G) return;
  int n0 = goff[g], n1 = goff[g+1];
  int cnt = n1 - n0;
  float acc = 0.f, acc2 = 0.f, wl = 0.f;
  if (lane < 48){
    wl = Wl[lane];
    const float* p = h3 + (size_t)n0*48 + lane;
    int i = 0;
    for (; i + 2 <= cnt; i += 2){ acc += p[(size_t)i*48]; acc2 += p[(size_t)(i+1)*48]; }
    if (i < cnt) acc += p[(size_t)i*48];
    acc += acc2;
  }
  float inv = 1.f / fmaxf((float)cnt, 1.f);
  float v = fmaxf(acc*inv, 0.f) * wl;
  for (int o = 32; o > 0; o >>= 1) v += __shfl_down(v, o);
  if (lane == 0){
    float logit = v + bl[0];
    outp[g] = 1.f / (1.f + __expf(-logit));
    float t = y[g];
    float sp = (logit > 0.f) ? (logit + log1pf(__expf(-logit))) : log1pf(__expf(logit));
    atomicAdd(lossAcc, sp - t*logit);
  }
}

__global__ void fin_k(const float* __restrict__ lossAcc, float* __restrict__ outp, int gtot){
  outp[gtot] = lossAcc[0] / (float)gtot;
}

// ---------------- launch ----------------
extern "C" void kernel_launch(void* const* d_in, const int* in_sizes, int n_in,
                              void* d_out, int out_size, void* d_ws, size_t ws_size,
                              hipStream_t stream)
{
  (void)n_in; (void)out_size; (void)ws_size;
  const float* x    = (const float*)d_in[0];
  const float* y    = (const float*)d_in[1];
  const int*  ei    = (const int*)d_in[2];
  const int*  batch = (const int*)d_in[3];
  const float* W1 = (const float*)d_in[4];
  const float* as1= (const float*)d_in[5];
  const float* ad1= (const float*)d_in[6];
  const float* b1 = (const float*)d_in[7];
  const float* W2 = (const float*)d_in[8];
  const float* as2= (const float*)d_in[9];
  const float* ad2= (const float*)d_in[10];
  const float* b2 = (const float*)d_in[11];
  const float* W3 = (const float*)d_in[12];
  const float* as3= (const float*)d_in[13];
  const float* ad3= (const float*)d_in[14];
  const float* b3 = (const float*)d_in[15];
  const float* Wl = (const float*)d_in[16];
  const float* bl = (const float*)d_in[17];
  float* outp = (float*)d_out;

  int Nn = in_sizes[0] / 128;   // 100000 (multiple of 16)
  int Gg = in_sizes[1];
  int Ee = in_sizes[2] / 2;
  int ET = Ee + Nn;

  char* p = (char*)d_ws;
  auto carve = [&](size_t bytes) -> void* {
    void* r = (void*)p; p += (bytes + 255) & ~(size_t)255; return r;
  };
  int*   off     = (int*)  carve((size_t)(Nn+1)*4);
  int*   cnt     = (int*)  carve((size_t)Nn*4);
  int*   csr     = (int*)  carve((size_t)ET*4);
  int*   rank    = (int*)  carve((size_t)ET*4);
  int*   bsum    = (int*)  carve(256*4);
  float* aS4     = (float*)carve((size_t)Nn*4*4);
  float* aD4     = (float*)carve((size_t)Nn*4*4);
  int*   goff    = (int*)  carve((size_t)(Gg+1)*4);
  float* lossAcc = (float*)carve(4);
  bf16*  WT1     = (bf16*) carve((size_t)(192+16)*128*2);
  bf16*  WT2     = (bf16*) carve((size_t)(96+16)*192*2);
  bf16*  WT3     = (bf16*) carve((size_t)(48+16)*96*2);
  bf16*  bufH    = (bf16*) carve((size_t)Nn*192*2);   // GEMM out (h), agg in
  bf16*  bufA    = (bf16*) carve((size_t)Nn*192*2);   // agg out / GEMM A-operand
  // layer-3 f32 out for pooling: alias into the unused tail of bufH's region
  float* bufO    = (float*)((char*)bufH + ((size_t)Nn*96 + 255 & ~(size_t)255));

  int NB = (Nn + 1023) / 1024;
  int ebk = (ET + THREADS - 1) / THREADS;

  // CSR by destination (atomic-free scatter via rank)
  hipMemsetAsync(cnt, 0, (size_t)Nn*4, stream);
  hist_k<<<ebk, THREADS, 0, stream>>>(ei, cnt, rank, Ee, ET);
  scan1_k<<<NB, 1024, 0, stream>>>(cnt, off, bsum, Nn);
  scan2_k<<<1, 256, 0, stream>>>(bsum, NB);
  scan3_k<<<NB, 1024, 0, stream>>>(off, bsum, Nn);
  scatter_k<<<ebk, THREADS, 0, stream>>>(ei, off, rank, csr, Ee, ET);

  // consolidated weight prep + graph boundaries (x->bf16 fused into gemm1)
  int prepTot = 24576 + 18432 + 4608 + 768 + 1152 + 576 + (Gg + 1);
  prep_k<<<(prepTot + THREADS-1)/THREADS, THREADS, 0, stream>>>(
      W1, as1, ad1, W2, as2, ad2, W3, as3, ad3, WT1, WT2, WT3, batch, goff, Nn, Gg);

  int nRT = Nn / 16;                 // 6250 row tiles
  int gx  = (nRT + 3) / 4;           // 4 waves/block
  int gb1 = (Nn + 3) / 4;            // GRP=64: 1 node/wave
  int gb2 = (Nn + 7) / 8;            // GRP=32: 2 nodes/wave
  int gb3 = (Nn + 15) / 16;          // GRP=16: 4 nodes/wave

  // layer 1: 128 -> 3x64 (A = x, f32, converted in-kernel)
  gemm_mfma_k<128,192,true><<<gx, 256, 0, stream>>>(x, WT1, bufH, aS4, aD4, nRT);
  agg_k<192,6,64><<<gb1, 256, 0, stream>>>(off, csr, bufH, aS4, aD4, b1, nullptr, bufA, Nn, 1);
  // layer 2: 192 -> 3x32
  gemm_mfma_k<192,96,false><<<gx, 256, 0, stream>>>(bufA, WT2, bufH, aS4, aD4, nRT);
  agg_k<96,5,32><<<gb2, 256, 0, stream>>>(off, csr, bufH, aS4, aD4, b2, nullptr, bufA, Nn, 1);
  // layer 3: 96 -> 3x16 (no ELU)
  gemm_mfma_k<96,48,false><<<gx, 256, 0, stream>>>(bufA, WT3, bufH, aS4, aD4, nRT);
  agg_k<48,4,16><<<gb3, 256, 0, stream>>>(off, csr, bufH, aS4, aD4, b3, bufO, nullptr, Nn, 0);

  // fused mean pool + relu + linear + sigmoid + BCE loss
  hipMemsetAsync(lossAcc, 0, 4, stream);
  pool_logits_k<<<(Gg + 3)/4, 256, 0, stream>>>(bufO, goff, Wl, bl, y, outp, lossAcc, Gg);
  fin_k<<<1, 1, 0, stream>>>(lossAcc, outp, Gg);
}